// Round 16
// baseline (38.513 us; speedup 1.0000x reference)
//
#include <hip/hip_runtime.h>
#include <hip/hip_bf16.h>
#include <hip/hip_fp16.h>

// ---------------------------------------------------------------------------
// TopologyBranch: persistence images (64x64, sigma=1) + 3-layer MLP
// Round 16: R14 structure (best passing, 38.5us) + round-to-nearest f16
//           packing in pi's Gaussian gen (rtz biased the all-positive
//           kernel values low; bias accumulated through 1000-pt sums ->
//           ~6e-3 absmax). gemm1 keeps rtz (W1 symmetric +/-, no bias).
// ---------------------------------------------------------------------------

#define P0_N 1024
#define P1_N 512

typedef _Float16 h2 __attribute__((ext_vector_type(2)));
typedef _Float16 f16x8 __attribute__((ext_vector_type(8)));
typedef float f32x4 __attribute__((ext_vector_type(4)));

// sqrt(0.5 * log2(e)): exp(-0.5*d^2) == exp2(-(S*d)^2)
#define KSCALE 0.849321804f
#define DG (KSCALE / 63.0f)          // scaled grid step

static __device__ __forceinline__ float fast_exp2(float x) {
#if defined(__has_builtin)
#if __has_builtin(__builtin_amdgcn_exp2f)
    return __builtin_amdgcn_exp2f(x);   // raw v_exp_f32
#else
    return exp2f(x);
#endif
#else
    return exp2f(x);
#endif
}

// round-toward-zero pack (OK for symmetric values, e.g. W1 weights)
static __device__ __forceinline__ h2 pk2(float a, float b) {
#if defined(__has_builtin)
#if __has_builtin(__builtin_amdgcn_cvt_pkrtz)
    return __builtin_bit_cast(h2, __builtin_amdgcn_cvt_pkrtz(a, b));  // v_cvt_pkrtz_f16_f32
#else
    h2 r; r[0] = (_Float16)a; r[1] = (_Float16)b; return r;
#endif
#else
    h2 r; r[0] = (_Float16)a; r[1] = (_Float16)b; return r;
#endif
}

// round-to-nearest pack (REQUIRED for all-positive values: rtz bias
// accumulates through large positive sums)
static __device__ __forceinline__ h2 pk2rn(float a, float b) {
    __half2 h = __floats2half2_rn(a, b);
    return __builtin_bit_cast(h2, h);
}

// ---------------------------- Kernel A: persistence image ------------------
// One 256-thread block per (batch, hom); hom-balance remap (R14). 64-point
// chunks: gen (8 pts x 1 col b128 stores, recurrence over 4 cols) -> MFMA.
__global__ __launch_bounds__(256) void pi_kernel(const float* __restrict__ p0,
                                                 const float* __restrict__ p1,
                                                 _Float16* __restrict__ featsH)
{
    const int bid  = blockIdx.x;          // 0..511
    const int task = ((bid & 255) << 1) | (bid >> 8);   // hom-balance remap
    const int b    = task >> 1;
    const int hom  = task & 1;
    const int P    = hom ? P1_N : P0_N;
    const float* pairs = hom ? (p1 + (size_t)b * P1_N * 2)
                             : (p0 + (size_t)b * P0_N * 2);
    const int t = threadIdx.x;
    const int w = t >> 6, lane = t & 63;

    __shared__ float cbs[1024], cps[1024], cws[1024];         // compacted, 12 KB
    __shared__ __align__(16) _Float16 kbT[64][72];            // [col][pt] 9 KB
    __shared__ __align__(16) _Float16 kpT[64][72];            // [col][pt] 9 KB
    __shared__ float wmn0[4], wmx0[4], wmn1[4], wmx1[4];
    __shared__ unsigned gcnt[16];

    // ---- Phase 1: load points (<=4 slots/thread), masked min/max ----
    float bv_[4], pv_[4];
    bool  val[4];
    float bmin = 1e30f, bmax = -1e30f, pmin = 1e30f, pmax = -1e30f;
    #pragma unroll
    for (int s = 0; s < 4; ++s) {
        const int p = t + s * 256;
        val[s] = false; bv_[s] = 0.0f; pv_[s] = 0.0f;
        if (p < P) {
            const float2 pr = ((const float2*)pairs)[p];
            const float birth = pr.x;
            const float pers  = pr.y - pr.x;
            bv_[s] = birth; pv_[s] = pers;
            val[s] = pers > 1e-6f;
            if (val[s]) {
                bmin = fminf(bmin, birth); bmax = fmaxf(bmax, birth);
                pmin = fminf(pmin, pers);  pmax = fmaxf(pmax, pers);
            }
        }
    }
    #pragma unroll
    for (int d = 32; d > 0; d >>= 1) {
        bmin = fminf(bmin, __shfl_xor(bmin, d));
        bmax = fmaxf(bmax, __shfl_xor(bmax, d));
        pmin = fminf(pmin, __shfl_xor(pmin, d));
        pmax = fmaxf(pmax, __shfl_xor(pmax, d));
    }
    unsigned long long msk[4];
    #pragma unroll
    for (int s = 0; s < 4; ++s) msk[s] = __ballot(val[s]);
    if (lane == 0) {
        wmn0[w] = bmin; wmx0[w] = bmax; wmn1[w] = pmin; wmx1[w] = pmax;
        #pragma unroll
        for (int s = 0; s < 4; ++s) gcnt[w * 4 + s] = (unsigned)__popcll(msk[s]);
    }
    __syncthreads();
    float bmn = fminf(fminf(wmn0[0], wmn0[1]), fminf(wmn0[2], wmn0[3]));
    float bmx = fmaxf(fmaxf(wmx0[0], wmx0[1]), fmaxf(wmx0[2], wmx0[3]));
    float pmn = fminf(fminf(wmn1[0], wmn1[1]), fminf(wmn1[2], wmn1[3]));
    float pmx = fmaxf(fmaxf(wmx1[0], wmx1[1]), fmaxf(wmx1[2], wmx1[3]));
    if (bmx - bmn < 1e-6f) { bmn = 0.0f; bmx = 1.0f; }
    if (pmx - pmn < 1e-6f) { pmn = 0.0f; pmx = 1.0f; }
    const float binv = KSCALE / (bmx - bmn + 1e-8f);   // exp2 scale folded in
    const float pinv = KSCALE / (pmx - pmn + 1e-8f);

    // prefix over the 16 group counts
    unsigned gb[4] = {0, 0, 0, 0};
    unsigned run = 0;
    #pragma unroll
    for (int g = 0; g < 16; ++g) {
        #pragma unroll
        for (int s = 0; s < 4; ++s)
            if (g == w * 4 + s) gb[s] = run;
        run += gcnt[g];
    }
    const int nv = (int)run;
    const int nchunks = (nv + 63) >> 6;

    // ---- Phase 2: scatter compacted normalized coords + weights ----
    const unsigned long long below = (1ull << lane) - 1ull;
    #pragma unroll
    for (int s = 0; s < 4; ++s) {
        if (val[s]) {
            const unsigned pos = gb[s] + (unsigned)__popcll(msk[s] & below);
            cbs[pos] = (bv_[s] - bmn) * binv;
            cps[pos] = (pv_[s] - pmn) * pinv;
            cws[pos] = pv_[s];
        }
    }
    for (int i = nv + t; i < nchunks * 64; i += 256) {
        cbs[i] = 0.0f; cps[i] = 0.0f; cws[i] = 0.0f;
    }

    // ---- Phase 3: per chunk: gen (b128 stores) then MFMA consume ----
    const int surf = t >> 7;
    const int rem  = t & 127;
    const int po   = rem & 7;
    const int cq   = rem >> 3;
    const float G0   = (float)(cq * 4) * DG;
    const float rho  = fast_exp2(-2.0f * DG * DG);
    const float c1q  = -DG * DG * (float)(8 * cq + 1);
    const float* Xarr = surf ? cps : cbs;
    _Float16* sT = surf ? &kpT[0][0] : &kbT[0][0];

    const int wm = (w >> 1) * 32, wn = (w & 1) * 32;
    const int fr = lane & 15, fg = lane >> 4;

    f32x4 acc[2][2] = {};

    __syncthreads();                       // compaction visible
    for (int c = 0; c < nchunks; ++c) {
        const int base = c * 64;
        {
            float v[8], r[8];
            #pragma unroll
            for (int p = 0; p < 8; ++p) {
                const float X = Xarr[base + po * 8 + p];
                const float W = surf ? 1.0f : cws[base + po * 8 + p];
                const float d = G0 - X;
                v[p] = W * fast_exp2(-(d * d));
                r[p] = fast_exp2(c1q + 2.0f * DG * X);
            }
            #pragma unroll
            for (int cc = 0; cc < 4; ++cc) {
                union { uint4 u; h2 h[4]; } pk;
                pk.h[0] = pk2rn(v[0], v[1]);
                pk.h[1] = pk2rn(v[2], v[3]);
                pk.h[2] = pk2rn(v[4], v[5]);
                pk.h[3] = pk2rn(v[6], v[7]);
                *(uint4*)&sT[(cq * 4 + cc) * 72 + po * 8] = pk.u;
                #pragma unroll
                for (int p = 0; p < 8; ++p) { v[p] *= r[p]; r[p] *= rho; }
            }
        }
        __syncthreads();
        #pragma unroll
        for (int ks2 = 0; ks2 < 64; ks2 += 32) {
            f16x8 af[2], bf[2];
            af[0] = *(const f16x8*)&kbT[wm + fr][ks2 + fg * 8];
            af[1] = *(const f16x8*)&kbT[wm + 16 + fr][ks2 + fg * 8];
            bf[0] = *(const f16x8*)&kpT[wn + fr][ks2 + fg * 8];
            bf[1] = *(const f16x8*)&kpT[wn + 16 + fr][ks2 + fg * 8];
            #pragma unroll
            for (int i = 0; i < 2; ++i)
                #pragma unroll
                for (int j = 0; j < 2; ++j)
                    acc[i][j] = __builtin_amdgcn_mfma_f32_16x16x32_f16(
                        af[i], bf[j], acc[i][j], 0, 0, 0);
        }
        __syncthreads();
    }

    // ---- Phase 4: write quadrant (C/D: col=lane&15, row=fg*4+r) ----
    _Float16* dst = featsH + (size_t)b * 8192 + hom * 4096;
    #pragma unroll
    for (int i = 0; i < 2; ++i)
        #pragma unroll
        for (int j = 0; j < 2; ++j) {
            const int r0_ = wm + i * 16 + fg * 4;
            const int cc  = wn + j * 16 + fr;
            #pragma unroll
            for (int r = 0; r < 4; ++r)
                dst[(size_t)(r0_ + r) * 64 + cc] = (_Float16)acc[i][j][r];
        }
}

// ---------------------------- Kernel B: GEMM1 via MFMA (R14) ---------------
// Split-K 16, b64 transpose staging, 2-deep register prefetch, XCD-aware
// block swizzle (mt-sharers of a W1 slab share bid%8 -> same XCD).
__global__ __launch_bounds__(256) void gemm1_mfma(const _Float16* __restrict__ Ah,
                                                  const float* __restrict__ W1,
                                                  float* __restrict__ part)
{
    const int bid = blockIdx.x;           // 0..511
    const int mt  = (bid >> 3) & 3;
    const int fid = (bid & 7) | ((bid >> 5) << 3);   // 0..127
    const int nt  = fid >> 4;             // 0..7
    const int ks  = fid & 15;             // 0..15
    const int t   = threadIdx.x;

    __shared__ _Float16 As[64][72];   // [m][k]
    __shared__ _Float16 Bs[64][72];   // [n][k]

    const int mbase = mt * 64, nbase = nt * 64, kbase = ks * 512;
    const int lrow = t >> 2, lk0 = (t & 3) * 16;
    const int k0s  = (t >> 4) * 4, nc = (t & 15) * 4;

    const _Float16* Ap = Ah + (size_t)(mbase + lrow) * 8192 + kbase + lk0;
    const float*    Wp = W1 + (size_t)(kbase + k0s) * 512 + nbase + nc;

    const int w = t >> 6, lane = t & 63;
    const int wm = (w >> 1) * 32, wn = (w & 1) * 32;
    const int fr = lane & 15, fg = lane >> 4;

    f32x4 acc[2][2] = {};

    auto stage = [&](const uint4& a0, const uint4& a1,
                     const float4& w0, const float4& w1,
                     const float4& w2, const float4& w3) {
        *(uint4*)&As[lrow][lk0]     = a0;
        *(uint4*)&As[lrow][lk0 + 8] = a1;
        union { uint2 u; h2 h[2]; } pk;
        pk.h[0] = pk2(w0.x, w1.x); pk.h[1] = pk2(w2.x, w3.x);
        *(uint2*)&Bs[nc + 0][k0s] = pk.u;
        pk.h[0] = pk2(w0.y, w1.y); pk.h[1] = pk2(w2.y, w3.y);
        *(uint2*)&Bs[nc + 1][k0s] = pk.u;
        pk.h[0] = pk2(w0.z, w1.z); pk.h[1] = pk2(w2.z, w3.z);
        *(uint2*)&Bs[nc + 2][k0s] = pk.u;
        pk.h[0] = pk2(w0.w, w1.w); pk.h[1] = pk2(w2.w, w3.w);
        *(uint2*)&Bs[nc + 3][k0s] = pk.u;
    };
    auto consume = [&]() {
        #pragma unroll
        for (int ks2 = 0; ks2 < 64; ks2 += 32) {
            f16x8 af[2], bf[2];
            af[0] = *(const f16x8*)&As[wm + fr][ks2 + fg * 8];
            af[1] = *(const f16x8*)&As[wm + 16 + fr][ks2 + fg * 8];
            bf[0] = *(const f16x8*)&Bs[wn + fr][ks2 + fg * 8];
            bf[1] = *(const f16x8*)&Bs[wn + 16 + fr][ks2 + fg * 8];
            #pragma unroll
            for (int i = 0; i < 2; ++i)
                #pragma unroll
                for (int j = 0; j < 2; ++j)
                    acc[i][j] = __builtin_amdgcn_mfma_f32_16x16x32_f16(
                        af[i], bf[j], acc[i][j], 0, 0, 0);
        }
    };
    auto loadA = [&](int k0, uint4& a0, uint4& a1) {
        a0 = *(const uint4*)(Ap + k0);
        a1 = *(const uint4*)(Ap + k0 + 8);
    };
    auto loadW = [&](int k0, float4& w0, float4& w1, float4& w2, float4& w3) {
        const float* p = Wp + (size_t)k0 * 512;
        w0 = *(const float4*)(p);
        w1 = *(const float4*)(p + 512);
        w2 = *(const float4*)(p + 1024);
        w3 = *(const float4*)(p + 1536);
    };

    uint4  a0A, a1A, a0B, a1B;
    float4 w0A, w1A, w2A, w3A, w0B, w1B, w2B, w3B;
    loadA(0,  a0A, a1A);  loadW(0,  w0A, w1A, w2A, w3A);
    loadA(64, a0B, a1B);  loadW(64, w0B, w1B, w2B, w3B);

    #pragma unroll
    for (int it2 = 0; it2 < 4; ++it2) {
        const int k0 = it2 * 128;
        __syncthreads();
        stage(a0A, a1A, w0A, w1A, w2A, w3A);
        __syncthreads();
        if (k0 + 128 < 512) {
            loadA(k0 + 128, a0A, a1A);
            loadW(k0 + 128, w0A, w1A, w2A, w3A);
        }
        consume();
        __syncthreads();
        stage(a0B, a1B, w0B, w1B, w2B, w3B);
        __syncthreads();
        if (k0 + 192 < 512) {
            loadA(k0 + 192, a0B, a1B);
            loadW(k0 + 192, w0B, w1B, w2B, w3B);
        }
        consume();
    }

    // C/D layout: col = lane&15, row = (lane>>4)*4 + reg
    #pragma unroll
    for (int i = 0; i < 2; ++i)
        #pragma unroll
        for (int j = 0; j < 2; ++j) {
            const int r0 = mbase + wm + i * 16 + fg * 4;
            const int c  = nbase + wn + j * 16 + fr;
            float* dst = part + (size_t)ks * (256 * 512) + (size_t)r0 * 512 + c;
            #pragma unroll
            for (int r = 0; r < 4; ++r) dst[(size_t)r * 512] = acc[i][j][r];
        }
}

// ---------------------------- Kernel C: fused tail (R9) --------------------
__global__ __launch_bounds__(1024) void tail_kernel(const float* __restrict__ part,
    const float* __restrict__ b1, const float* __restrict__ g1, const float* __restrict__ be1,
    const float* __restrict__ W2, const float* __restrict__ b2, const float* __restrict__ g2, const float* __restrict__ be2,
    const float* __restrict__ W3, const float* __restrict__ b3,
    float* __restrict__ out)
{
    const int row  = blockIdx.x;
    const int t    = threadIdx.x;
    const int wid  = t >> 6, lane = t & 63;

    __shared__ float h1s[512];
    __shared__ float h2s[256];
    __shared__ float red[1024];
    __shared__ __align__(16) float red4[1024][4];   // 16 KB
    __shared__ float wredA[16], wredB[16];

    // ---- Phase 1: reduce split-K partials (16 slabs) + bias ----
    const int col = t & 511, sb8 = (t >> 9) * 8;
    float v = 0.0f;
    #pragma unroll
    for (int s = 0; s < 8; ++s)
        v += part[(size_t)(sb8 + s) * (256 * 512) + (size_t)row * 512 + col];
    red[t] = v;
    __syncthreads();
    float x = 0.0f;
    if (t < 512) x = red[t] + red[t + 512] + b1[col];

    // ---- LN over 512 ----
    float s1 = (t < 512) ? x : 0.0f;
    float s2 = (t < 512) ? x * x : 0.0f;
    #pragma unroll
    for (int d = 32; d > 0; d >>= 1) {
        s1 += __shfl_xor(s1, d);
        s2 += __shfl_xor(s2, d);
    }
    if (lane == 0) { wredA[wid] = s1; wredB[wid] = s2; }
    __syncthreads();
    float mu = 0.0f, m2 = 0.0f;
    #pragma unroll
    for (int i = 0; i < 16; ++i) { mu += wredA[i]; m2 += wredB[i]; }
    mu *= (1.0f / 512.0f);
    m2  = m2 * (1.0f / 512.0f) - mu * mu;
    const float rs = rsqrtf(m2 + 1e-5f);
    if (t < 512) h1s[col] = fmaxf((x - mu) * rs * g1[col] + be1[col], 0.0f);
    __syncthreads();

    // ---- GEMM2: 64 col-groups (float4) x 16-way K-split (32 k each) ----
    const int cg2 = t & 63, ksl = t >> 6;
    {
        float4 a4 = make_float4(0.0f, 0.0f, 0.0f, 0.0f);
        const float* w2p = W2 + (size_t)(ksl * 32) * 256 + cg2 * 4;
        const float* h1p = h1s + ksl * 32;
        #pragma unroll 8
        for (int k = 0; k < 32; ++k) {
            const float4 wv = *(const float4*)(w2p + (size_t)k * 256);
            const float hv = h1p[k];
            a4.x += hv * wv.x; a4.y += hv * wv.y;
            a4.z += hv * wv.z; a4.w += hv * wv.w;
        }
        *(float4*)red4[t] = a4;
    }
    __syncthreads();
    float y = 0.0f;
    if (t < 256) {
        const float* r4f = (const float*)red4;
        const int base = (t >> 2) * 4 + (t & 3);
        #pragma unroll
        for (int s = 0; s < 16; ++s) y += r4f[s * 256 + base];
        y += b2[t];
    }

    // ---- LN over 256 ----
    s1 = (t < 256) ? y : 0.0f;
    s2 = (t < 256) ? y * y : 0.0f;
    #pragma unroll
    for (int d = 32; d > 0; d >>= 1) {
        s1 += __shfl_xor(s1, d);
        s2 += __shfl_xor(s2, d);
    }
    if (lane == 0) { wredA[wid] = s1; wredB[wid] = s2; }
    __syncthreads();
    mu = 0.0f; m2 = 0.0f;
    #pragma unroll
    for (int i = 0; i < 16; ++i) { mu += wredA[i]; m2 += wredB[i]; }
    mu *= (1.0f / 256.0f);
    m2  = m2 * (1.0f / 256.0f) - mu * mu;
    const float rs2 = rsqrtf(m2 + 1e-5f);
    if (t < 256) h2s[t] = fmaxf((y - mu) * rs2 * g2[t] + be2[t], 0.0f);
    __syncthreads();

    // ---- GEMM3: 128 cols x 8-way K-split ----
    const int col3 = t & 127, ks3 = t >> 7;
    float o = 0.0f;
    #pragma unroll 8
    for (int k = 0; k < 32; ++k)
        o += h2s[ks3 * 32 + k] * W3[(size_t)(ks3 * 32 + k) * 128 + col3];
    red[t] = o;
    __syncthreads();
    if (t < 128) {
        float oo = 0.0f;
        #pragma unroll
        for (int s = 0; s < 8; ++s) oo += red[t + s * 128];
        out[(size_t)row * 128 + t] = oo + b3[t];
    }
}

// ---------------------------------------------------------------------------
extern "C" void kernel_launch(void* const* d_in, const int* in_sizes, int n_in,
                              void* d_out, int out_size, void* d_ws, size_t ws_size,
                              hipStream_t stream)
{
    const float* p0  = (const float*)d_in[0];
    const float* p1  = (const float*)d_in[1];
    const float* W1  = (const float*)d_in[2];
    const float* b1  = (const float*)d_in[3];
    const float* g1  = (const float*)d_in[4];
    const float* be1 = (const float*)d_in[5];
    const float* W2  = (const float*)d_in[6];
    const float* b2  = (const float*)d_in[7];
    const float* g2  = (const float*)d_in[8];
    const float* be2 = (const float*)d_in[9];
    const float* W3  = (const float*)d_in[10];
    const float* b3  = (const float*)d_in[11];
    float* out = (float*)d_out;

    // workspace: featsH 4MB | part 8MB (16 split-K slabs)
    _Float16* featsH = (_Float16*)d_ws;
    float*    part   = (float*)((char*)d_ws + (4u << 20));

    hipLaunchKernelGGL(pi_kernel,    dim3(512),      dim3(256),  0, stream, p0, p1, featsH);
    hipLaunchKernelGGL(gemm1_mfma,   dim3(512),      dim3(256),  0, stream, featsH, W1, part);
    hipLaunchKernelGGL(tail_kernel,  dim3(256),      dim3(1024), 0, stream, part,
                       b1, g1, be1, W2, b2, g2, be2, W3, b3, out);
}

// Round 18
// 36.535 us; speedup vs baseline: 1.0542x; 1.0542x over previous
//
#include <hip/hip_runtime.h>
#include <hip/hip_bf16.h>
#include <hip/hip_fp16.h>

// ---------------------------------------------------------------------------
// TopologyBranch: persistence images (64x64, sigma=1) + 3-layer MLP
// Round 18 (= R17 resubmit after infra failure): R16 + f16 split-K partials —
//           the part buffer (8MB w + 8MB r in f32) was the largest remaining
//           intermediate round-trip; f16 halves it. rn packing (bias-free).
//           All else frozen at R16.
// ---------------------------------------------------------------------------

#define P0_N 1024
#define P1_N 512

typedef _Float16 h2 __attribute__((ext_vector_type(2)));
typedef _Float16 f16x8 __attribute__((ext_vector_type(8)));
typedef float f32x4 __attribute__((ext_vector_type(4)));

// sqrt(0.5 * log2(e)): exp(-0.5*d^2) == exp2(-(S*d)^2)
#define KSCALE 0.849321804f
#define DG (KSCALE / 63.0f)          // scaled grid step

static __device__ __forceinline__ float fast_exp2(float x) {
#if defined(__has_builtin)
#if __has_builtin(__builtin_amdgcn_exp2f)
    return __builtin_amdgcn_exp2f(x);   // raw v_exp_f32
#else
    return exp2f(x);
#endif
#else
    return exp2f(x);
#endif
}

// round-toward-zero pack (OK for symmetric values, e.g. W1 weights)
static __device__ __forceinline__ h2 pk2(float a, float b) {
#if defined(__has_builtin)
#if __has_builtin(__builtin_amdgcn_cvt_pkrtz)
    return __builtin_bit_cast(h2, __builtin_amdgcn_cvt_pkrtz(a, b));  // v_cvt_pkrtz_f16_f32
#else
    h2 r; r[0] = (_Float16)a; r[1] = (_Float16)b; return r;
#endif
#else
    h2 r; r[0] = (_Float16)a; r[1] = (_Float16)b; return r;
#endif
}

// round-to-nearest pack (REQUIRED for all-positive / accumulated values)
static __device__ __forceinline__ h2 pk2rn(float a, float b) {
    __half2 h = __floats2half2_rn(a, b);
    return __builtin_bit_cast(h2, h);
}

// ---------------------------- Kernel A: persistence image (R16) ------------
__global__ __launch_bounds__(256) void pi_kernel(const float* __restrict__ p0,
                                                 const float* __restrict__ p1,
                                                 _Float16* __restrict__ featsH)
{
    const int bid  = blockIdx.x;          // 0..511
    const int task = ((bid & 255) << 1) | (bid >> 8);   // hom-balance remap
    const int b    = task >> 1;
    const int hom  = task & 1;
    const int P    = hom ? P1_N : P0_N;
    const float* pairs = hom ? (p1 + (size_t)b * P1_N * 2)
                             : (p0 + (size_t)b * P0_N * 2);
    const int t = threadIdx.x;
    const int w = t >> 6, lane = t & 63;

    __shared__ float cbs[1024], cps[1024], cws[1024];         // compacted, 12 KB
    __shared__ __align__(16) _Float16 kbT[64][72];            // [col][pt] 9 KB
    __shared__ __align__(16) _Float16 kpT[64][72];            // [col][pt] 9 KB
    __shared__ float wmn0[4], wmx0[4], wmn1[4], wmx1[4];
    __shared__ unsigned gcnt[16];

    // ---- Phase 1: load points (<=4 slots/thread), masked min/max ----
    float bv_[4], pv_[4];
    bool  val[4];
    float bmin = 1e30f, bmax = -1e30f, pmin = 1e30f, pmax = -1e30f;
    #pragma unroll
    for (int s = 0; s < 4; ++s) {
        const int p = t + s * 256;
        val[s] = false; bv_[s] = 0.0f; pv_[s] = 0.0f;
        if (p < P) {
            const float2 pr = ((const float2*)pairs)[p];
            const float birth = pr.x;
            const float pers  = pr.y - pr.x;
            bv_[s] = birth; pv_[s] = pers;
            val[s] = pers > 1e-6f;
            if (val[s]) {
                bmin = fminf(bmin, birth); bmax = fmaxf(bmax, birth);
                pmin = fminf(pmin, pers);  pmax = fmaxf(pmax, pers);
            }
        }
    }
    #pragma unroll
    for (int d = 32; d > 0; d >>= 1) {
        bmin = fminf(bmin, __shfl_xor(bmin, d));
        bmax = fmaxf(bmax, __shfl_xor(bmax, d));
        pmin = fminf(pmin, __shfl_xor(pmin, d));
        pmax = fmaxf(pmax, __shfl_xor(pmax, d));
    }
    unsigned long long msk[4];
    #pragma unroll
    for (int s = 0; s < 4; ++s) msk[s] = __ballot(val[s]);
    if (lane == 0) {
        wmn0[w] = bmin; wmx0[w] = bmax; wmn1[w] = pmin; wmx1[w] = pmax;
        #pragma unroll
        for (int s = 0; s < 4; ++s) gcnt[w * 4 + s] = (unsigned)__popcll(msk[s]);
    }
    __syncthreads();
    float bmn = fminf(fminf(wmn0[0], wmn0[1]), fminf(wmn0[2], wmn0[3]));
    float bmx = fmaxf(fmaxf(wmx0[0], wmx0[1]), fmaxf(wmx0[2], wmx0[3]));
    float pmn = fminf(fminf(wmn1[0], wmn1[1]), fminf(wmn1[2], wmn1[3]));
    float pmx = fmaxf(fmaxf(wmx1[0], wmx1[1]), fmaxf(wmx1[2], wmx1[3]));
    if (bmx - bmn < 1e-6f) { bmn = 0.0f; bmx = 1.0f; }
    if (pmx - pmn < 1e-6f) { pmn = 0.0f; pmx = 1.0f; }
    const float binv = KSCALE / (bmx - bmn + 1e-8f);   // exp2 scale folded in
    const float pinv = KSCALE / (pmx - pmn + 1e-8f);

    // prefix over the 16 group counts
    unsigned gb[4] = {0, 0, 0, 0};
    unsigned run = 0;
    #pragma unroll
    for (int g = 0; g < 16; ++g) {
        #pragma unroll
        for (int s = 0; s < 4; ++s)
            if (g == w * 4 + s) gb[s] = run;
        run += gcnt[g];
    }
    const int nv = (int)run;
    const int nchunks = (nv + 63) >> 6;

    // ---- Phase 2: scatter compacted normalized coords + weights ----
    const unsigned long long below = (1ull << lane) - 1ull;
    #pragma unroll
    for (int s = 0; s < 4; ++s) {
        if (val[s]) {
            const unsigned pos = gb[s] + (unsigned)__popcll(msk[s] & below);
            cbs[pos] = (bv_[s] - bmn) * binv;
            cps[pos] = (pv_[s] - pmn) * pinv;
            cws[pos] = pv_[s];
        }
    }
    for (int i = nv + t; i < nchunks * 64; i += 256) {
        cbs[i] = 0.0f; cps[i] = 0.0f; cws[i] = 0.0f;
    }

    // ---- Phase 3: per chunk: gen (b128 stores) then MFMA consume ----
    const int surf = t >> 7;
    const int rem  = t & 127;
    const int po   = rem & 7;
    const int cq   = rem >> 3;
    const float G0   = (float)(cq * 4) * DG;
    const float rho  = fast_exp2(-2.0f * DG * DG);
    const float c1q  = -DG * DG * (float)(8 * cq + 1);
    const float* Xarr = surf ? cps : cbs;
    _Float16* sT = surf ? &kpT[0][0] : &kbT[0][0];

    const int wm = (w >> 1) * 32, wn = (w & 1) * 32;
    const int fr = lane & 15, fg = lane >> 4;

    f32x4 acc[2][2] = {};

    __syncthreads();                       // compaction visible
    for (int c = 0; c < nchunks; ++c) {
        const int base = c * 64;
        {
            float v[8], r[8];
            #pragma unroll
            for (int p = 0; p < 8; ++p) {
                const float X = Xarr[base + po * 8 + p];
                const float W = surf ? 1.0f : cws[base + po * 8 + p];
                const float d = G0 - X;
                v[p] = W * fast_exp2(-(d * d));
                r[p] = fast_exp2(c1q + 2.0f * DG * X);
            }
            #pragma unroll
            for (int cc = 0; cc < 4; ++cc) {
                union { uint4 u; h2 h[4]; } pk;
                pk.h[0] = pk2rn(v[0], v[1]);
                pk.h[1] = pk2rn(v[2], v[3]);
                pk.h[2] = pk2rn(v[4], v[5]);
                pk.h[3] = pk2rn(v[6], v[7]);
                *(uint4*)&sT[(cq * 4 + cc) * 72 + po * 8] = pk.u;
                #pragma unroll
                for (int p = 0; p < 8; ++p) { v[p] *= r[p]; r[p] *= rho; }
            }
        }
        __syncthreads();
        #pragma unroll
        for (int ks2 = 0; ks2 < 64; ks2 += 32) {
            f16x8 af[2], bf[2];
            af[0] = *(const f16x8*)&kbT[wm + fr][ks2 + fg * 8];
            af[1] = *(const f16x8*)&kbT[wm + 16 + fr][ks2 + fg * 8];
            bf[0] = *(const f16x8*)&kpT[wn + fr][ks2 + fg * 8];
            bf[1] = *(const f16x8*)&kpT[wn + 16 + fr][ks2 + fg * 8];
            #pragma unroll
            for (int i = 0; i < 2; ++i)
                #pragma unroll
                for (int j = 0; j < 2; ++j)
                    acc[i][j] = __builtin_amdgcn_mfma_f32_16x16x32_f16(
                        af[i], bf[j], acc[i][j], 0, 0, 0);
        }
        __syncthreads();
    }

    // ---- Phase 4: write quadrant (C/D: col=lane&15, row=fg*4+r) ----
    _Float16* dst = featsH + (size_t)b * 8192 + hom * 4096;
    #pragma unroll
    for (int i = 0; i < 2; ++i)
        #pragma unroll
        for (int j = 0; j < 2; ++j) {
            const int r0_ = wm + i * 16 + fg * 4;
            const int cc  = wn + j * 16 + fr;
            #pragma unroll
            for (int r = 0; r < 4; ++r)
                dst[(size_t)(r0_ + r) * 64 + cc] = (_Float16)acc[i][j][r];
        }
}

// ---------------------------- Kernel B: GEMM1 via MFMA ---------------------
// Split-K 16, b64 transpose staging, 2-deep register prefetch, XCD-aware
// block swizzle. Partials written as f16 (rn) — halves part traffic.
__global__ __launch_bounds__(256) void gemm1_mfma(const _Float16* __restrict__ Ah,
                                                  const float* __restrict__ W1,
                                                  _Float16* __restrict__ part)
{
    const int bid = blockIdx.x;           // 0..511
    const int mt  = (bid >> 3) & 3;
    const int fid = (bid & 7) | ((bid >> 5) << 3);   // 0..127
    const int nt  = fid >> 4;             // 0..7
    const int ks  = fid & 15;             // 0..15
    const int t   = threadIdx.x;

    __shared__ _Float16 As[64][72];   // [m][k]
    __shared__ _Float16 Bs[64][72];   // [n][k]

    const int mbase = mt * 64, nbase = nt * 64, kbase = ks * 512;
    const int lrow = t >> 2, lk0 = (t & 3) * 16;
    const int k0s  = (t >> 4) * 4, nc = (t & 15) * 4;

    const _Float16* Ap = Ah + (size_t)(mbase + lrow) * 8192 + kbase + lk0;
    const float*    Wp = W1 + (size_t)(kbase + k0s) * 512 + nbase + nc;

    const int w = t >> 6, lane = t & 63;
    const int wm = (w >> 1) * 32, wn = (w & 1) * 32;
    const int fr = lane & 15, fg = lane >> 4;

    f32x4 acc[2][2] = {};

    auto stage = [&](const uint4& a0, const uint4& a1,
                     const float4& w0, const float4& w1,
                     const float4& w2, const float4& w3) {
        *(uint4*)&As[lrow][lk0]     = a0;
        *(uint4*)&As[lrow][lk0 + 8] = a1;
        union { uint2 u; h2 h[2]; } pk;
        pk.h[0] = pk2(w0.x, w1.x); pk.h[1] = pk2(w2.x, w3.x);
        *(uint2*)&Bs[nc + 0][k0s] = pk.u;
        pk.h[0] = pk2(w0.y, w1.y); pk.h[1] = pk2(w2.y, w3.y);
        *(uint2*)&Bs[nc + 1][k0s] = pk.u;
        pk.h[0] = pk2(w0.z, w1.z); pk.h[1] = pk2(w2.z, w3.z);
        *(uint2*)&Bs[nc + 2][k0s] = pk.u;
        pk.h[0] = pk2(w0.w, w1.w); pk.h[1] = pk2(w2.w, w3.w);
        *(uint2*)&Bs[nc + 3][k0s] = pk.u;
    };
    auto consume = [&]() {
        #pragma unroll
        for (int ks2 = 0; ks2 < 64; ks2 += 32) {
            f16x8 af[2], bf[2];
            af[0] = *(const f16x8*)&As[wm + fr][ks2 + fg * 8];
            af[1] = *(const f16x8*)&As[wm + 16 + fr][ks2 + fg * 8];
            bf[0] = *(const f16x8*)&Bs[wn + fr][ks2 + fg * 8];
            bf[1] = *(const f16x8*)&Bs[wn + 16 + fr][ks2 + fg * 8];
            #pragma unroll
            for (int i = 0; i < 2; ++i)
                #pragma unroll
                for (int j = 0; j < 2; ++j)
                    acc[i][j] = __builtin_amdgcn_mfma_f32_16x16x32_f16(
                        af[i], bf[j], acc[i][j], 0, 0, 0);
        }
    };
    auto loadA = [&](int k0, uint4& a0, uint4& a1) {
        a0 = *(const uint4*)(Ap + k0);
        a1 = *(const uint4*)(Ap + k0 + 8);
    };
    auto loadW = [&](int k0, float4& w0, float4& w1, float4& w2, float4& w3) {
        const float* p = Wp + (size_t)k0 * 512;
        w0 = *(const float4*)(p);
        w1 = *(const float4*)(p + 512);
        w2 = *(const float4*)(p + 1024);
        w3 = *(const float4*)(p + 1536);
    };

    uint4  a0A, a1A, a0B, a1B;
    float4 w0A, w1A, w2A, w3A, w0B, w1B, w2B, w3B;
    loadA(0,  a0A, a1A);  loadW(0,  w0A, w1A, w2A, w3A);
    loadA(64, a0B, a1B);  loadW(64, w0B, w1B, w2B, w3B);

    #pragma unroll
    for (int it2 = 0; it2 < 4; ++it2) {
        const int k0 = it2 * 128;
        __syncthreads();
        stage(a0A, a1A, w0A, w1A, w2A, w3A);
        __syncthreads();
        if (k0 + 128 < 512) {
            loadA(k0 + 128, a0A, a1A);
            loadW(k0 + 128, w0A, w1A, w2A, w3A);
        }
        consume();
        __syncthreads();
        stage(a0B, a1B, w0B, w1B, w2B, w3B);
        __syncthreads();
        if (k0 + 192 < 512) {
            loadA(k0 + 192, a0B, a1B);
            loadW(k0 + 192, w0B, w1B, w2B, w3B);
        }
        consume();
    }

    // C/D layout: col = lane&15, row = (lane>>4)*4 + reg; f16 rn partials
    #pragma unroll
    for (int i = 0; i < 2; ++i)
        #pragma unroll
        for (int j = 0; j < 2; ++j) {
            const int r0 = mbase + wm + i * 16 + fg * 4;
            const int c  = nbase + wn + j * 16 + fr;
            _Float16* dst = part + (size_t)ks * (256 * 512) + (size_t)r0 * 512 + c;
            #pragma unroll
            for (int r = 0; r < 4; ++r) {
                __half hv = __float2half_rn(acc[i][j][r]);
                dst[(size_t)r * 512] = __builtin_bit_cast(_Float16, hv);
            }
        }
}

// ---------------------------- Kernel C: fused tail -------------------------
__global__ __launch_bounds__(1024) void tail_kernel(const _Float16* __restrict__ part,
    const float* __restrict__ b1, const float* __restrict__ g1, const float* __restrict__ be1,
    const float* __restrict__ W2, const float* __restrict__ b2, const float* __restrict__ g2, const float* __restrict__ be2,
    const float* __restrict__ W3, const float* __restrict__ b3,
    float* __restrict__ out)
{
    const int row  = blockIdx.x;
    const int t    = threadIdx.x;
    const int wid  = t >> 6, lane = t & 63;

    __shared__ float h1s[512];
    __shared__ float h2s[256];
    __shared__ float red[1024];
    __shared__ __align__(16) float red4[1024][4];   // 16 KB
    __shared__ float wredA[16], wredB[16];

    // ---- Phase 1: reduce split-K partials (16 slabs, f16) + bias ----
    const int col = t & 511, sb8 = (t >> 9) * 8;
    float v = 0.0f;
    #pragma unroll
    for (int s = 0; s < 8; ++s)
        v += (float)part[(size_t)(sb8 + s) * (256 * 512) + (size_t)row * 512 + col];
    red[t] = v;
    __syncthreads();
    float x = 0.0f;
    if (t < 512) x = red[t] + red[t + 512] + b1[col];

    // ---- LN over 512 ----
    float s1 = (t < 512) ? x : 0.0f;
    float s2 = (t < 512) ? x * x : 0.0f;
    #pragma unroll
    for (int d = 32; d > 0; d >>= 1) {
        s1 += __shfl_xor(s1, d);
        s2 += __shfl_xor(s2, d);
    }
    if (lane == 0) { wredA[wid] = s1; wredB[wid] = s2; }
    __syncthreads();
    float mu = 0.0f, m2 = 0.0f;
    #pragma unroll
    for (int i = 0; i < 16; ++i) { mu += wredA[i]; m2 += wredB[i]; }
    mu *= (1.0f / 512.0f);
    m2  = m2 * (1.0f / 512.0f) - mu * mu;
    const float rs = rsqrtf(m2 + 1e-5f);
    if (t < 512) h1s[col] = fmaxf((x - mu) * rs * g1[col] + be1[col], 0.0f);
    __syncthreads();

    // ---- GEMM2: 64 col-groups (float4) x 16-way K-split (32 k each) ----
    const int cg2 = t & 63, ksl = t >> 6;
    {
        float4 a4 = make_float4(0.0f, 0.0f, 0.0f, 0.0f);
        const float* w2p = W2 + (size_t)(ksl * 32) * 256 + cg2 * 4;
        const float* h1p = h1s + ksl * 32;
        #pragma unroll 8
        for (int k = 0; k < 32; ++k) {
            const float4 wv = *(const float4*)(w2p + (size_t)k * 256);
            const float hv = h1p[k];
            a4.x += hv * wv.x; a4.y += hv * wv.y;
            a4.z += hv * wv.z; a4.w += hv * wv.w;
        }
        *(float4*)red4[t] = a4;
    }
    __syncthreads();
    float y = 0.0f;
    if (t < 256) {
        const float* r4f = (const float*)red4;
        const int base = (t >> 2) * 4 + (t & 3);
        #pragma unroll
        for (int s = 0; s < 16; ++s) y += r4f[s * 256 + base];
        y += b2[t];
    }

    // ---- LN over 256 ----
    s1 = (t < 256) ? y : 0.0f;
    s2 = (t < 256) ? y * y : 0.0f;
    #pragma unroll
    for (int d = 32; d > 0; d >>= 1) {
        s1 += __shfl_xor(s1, d);
        s2 += __shfl_xor(s2, d);
    }
    if (lane == 0) { wredA[wid] = s1; wredB[wid] = s2; }
    __syncthreads();
    mu = 0.0f; m2 = 0.0f;
    #pragma unroll
    for (int i = 0; i < 16; ++i) { mu += wredA[i]; m2 += wredB[i]; }
    mu *= (1.0f / 256.0f);
    m2  = m2 * (1.0f / 256.0f) - mu * mu;
    const float rs2 = rsqrtf(m2 + 1e-5f);
    if (t < 256) h2s[t] = fmaxf((y - mu) * rs2 * g2[t] + be2[t], 0.0f);
    __syncthreads();

    // ---- GEMM3: 128 cols x 8-way K-split ----
    const int col3 = t & 127, ks3 = t >> 7;
    float o = 0.0f;
    #pragma unroll 8
    for (int k = 0; k < 32; ++k)
        o += h2s[ks3 * 32 + k] * W3[(size_t)(ks3 * 32 + k) * 128 + col3];
    red[t] = o;
    __syncthreads();
    if (t < 128) {
        float oo = 0.0f;
        #pragma unroll
        for (int s = 0; s < 8; ++s) oo += red[t + s * 128];
        out[(size_t)row * 128 + t] = oo + b3[t];
    }
}

// ---------------------------------------------------------------------------
extern "C" void kernel_launch(void* const* d_in, const int* in_sizes, int n_in,
                              void* d_out, int out_size, void* d_ws, size_t ws_size,
                              hipStream_t stream)
{
    const float* p0  = (const float*)d_in[0];
    const float* p1  = (const float*)d_in[1];
    const float* W1  = (const float*)d_in[2];
    const float* b1  = (const float*)d_in[3];
    const float* g1  = (const float*)d_in[4];
    const float* be1 = (const float*)d_in[5];
    const float* W2  = (const float*)d_in[6];
    const float* b2  = (const float*)d_in[7];
    const float* g2  = (const float*)d_in[8];
    const float* be2 = (const float*)d_in[9];
    const float* W3  = (const float*)d_in[10];
    const float* b3  = (const float*)d_in[11];
    float* out = (float*)d_out;

    // workspace: featsH 4MB | part 4MB (16 f16 split-K slabs)
    _Float16* featsH = (_Float16*)d_ws;
    _Float16* part   = (_Float16*)((char*)d_ws + (4u << 20));

    hipLaunchKernelGGL(pi_kernel,    dim3(512),      dim3(256),  0, stream, p0, p1, featsH);
    hipLaunchKernelGGL(gemm1_mfma,   dim3(512),      dim3(256),  0, stream, featsH, W1, part);
    hipLaunchKernelGGL(tail_kernel,  dim3(256),      dim3(1024), 0, stream, part,
                       b1, g1, be1, W2, b2, g2, be2, W3, b3, out);
}